// Round 1
// baseline (8391.332 us; speedup 1.0000x reference)
//
#include <hip/hip_runtime.h>
#include <stdint.h>
#include <stddef.h>

typedef _Float16 half_t;
typedef __attribute__((ext_vector_type(8))) _Float16 halfx8;
typedef __attribute__((ext_vector_type(4))) float floatx4;

__device__ __forceinline__ float sigmoidf_(float x) { return 1.f / (1.f + __expf(-x)); }
__device__ __forceinline__ float tanhf_(float x) {
  x = fminf(fmaxf(x, -15.f), 15.f);
  float e = __expf(2.f * x);
  return (e - 1.f) / (e + 1.f);
}

__device__ __forceinline__ floatx4 mfma16(halfx8 a, halfx8 b, floatx4 c) {
  return __builtin_amdgcn_mfma_f32_16x16x32_f16(a, b, c, 0, 0, 0);
}

// ---------------- fp32 -> fp16 convert with optional row/col zero-pad ----------------
__global__ void convert_pad(const float* __restrict__ src, half_t* __restrict__ dst,
                            int srcRows, int srcCols, int dstRows, int dstCols) {
  int total = dstRows * dstCols;
  for (int i = blockIdx.x * blockDim.x + threadIdx.x; i < total; i += gridDim.x * blockDim.x) {
    int r = i / dstCols, c = i - r * dstCols;
    float v = (r < srcRows && c < srcCols) ? src[(size_t)r * srcCols + c] : 0.f;
    dst[i] = (half_t)v;
  }
}

// ---------------- repack W (rows x 256, fp32) into MFMA B-frag order -------------------
// dst[nt][ks][lane][j] = W[nt*16 + (lane&15)][ks*32 + (lane>>4)*8 + j], fp16.
// A wave reading dst + (nt*8+ks)*64*8 + lane*8 gets its B fragment via one
// fully coalesced 1KB global_load_dwordx4.
__global__ void repack_bfrag(const float* __restrict__ src, half_t* __restrict__ dst,
                             int ntCount, int srcRows) {
  int total = ntCount * 8 * 64 * 8;
  for (int i = blockIdx.x * blockDim.x + threadIdx.x; i < total; i += gridDim.x * blockDim.x) {
    int j = i & 7, lane = (i >> 3) & 63, ks = (i >> 9) & 7, nt = i >> 12;
    int q = lane >> 4, m15 = lane & 15;
    int row = nt * 16 + m15;
    int col = ks * 32 + q * 8 + j;
    float v = (row < srcRows) ? src[(size_t)row * 256 + col] : 0.f;
    dst[i] = (half_t)v;
  }
}

// ---------------- GEMM: C(MxN,fp32) = relu(A(MxKa,fp32) * B(NxKp,fp16)^T + bias) ------
__global__ __launch_bounds__(256) void gemm_bias_relu(
    const float* __restrict__ A, int lda, int Ka,
    const half_t* __restrict__ B, int ldb,
    const float* __restrict__ bias,
    float* __restrict__ C, int N, int Kp) {
  __shared__ half_t As[128 * 64];
  __shared__ half_t Bs[128 * 64];
  const int t = threadIdx.x;
  const int w = t >> 6, l = t & 63;
  const int q = l >> 4, m15 = l & 15;
  const int rowBase = blockIdx.x * 128, colBase = blockIdx.y * 128;
  const int wm = (w >> 1) * 64, wn = (w & 1) * 64;
  const floatx4 z4 = {0.f, 0.f, 0.f, 0.f};
  floatx4 acc[4][4];
#pragma unroll
  for (int i = 0; i < 4; ++i)
#pragma unroll
    for (int j = 0; j < 4; ++j) acc[i][j] = z4;

  const int sr = t >> 3;
  const int sc = (t & 7) * 8;

  for (int k0 = 0; k0 < Kp; k0 += 64) {
    __syncthreads();
    const bool full = (k0 + 64 <= Ka);
#pragma unroll
    for (int p = 0; p < 4; ++p) {
      const int r = p * 32 + sr;
      halfx8 tmp;
      if (full) {
        const float4* s0 = (const float4*)(A + (size_t)(rowBase + r) * lda + k0 + sc);
        float4 f0 = s0[0], f1 = s0[1];
        tmp[0] = (half_t)f0.x; tmp[1] = (half_t)f0.y; tmp[2] = (half_t)f0.z; tmp[3] = (half_t)f0.w;
        tmp[4] = (half_t)f1.x; tmp[5] = (half_t)f1.y; tmp[6] = (half_t)f1.z; tmp[7] = (half_t)f1.w;
      } else {
#pragma unroll
        for (int j2 = 0; j2 < 8; ++j2) {
          int kk = k0 + sc + j2;
          tmp[j2] = (half_t)(kk < Ka ? A[(size_t)(rowBase + r) * lda + kk] : 0.f);
        }
      }
      *(halfx8*)(&As[r * 64 + sc]) = tmp;
    }
#pragma unroll
    for (int p = 0; p < 4; ++p) {
      const int chunk = p * 256 + t;
      const int r = chunk >> 3, cc = (chunk & 7) * 8;
      *(halfx8*)(&Bs[r * 64 + cc]) =
          *(const halfx8*)(B + (size_t)(colBase + r) * ldb + k0 + cc);
    }
    __syncthreads();
#pragma unroll
    for (int kk = 0; kk < 2; ++kk) {
      const int ko = kk * 32 + q * 8;
      halfx8 af[4], bfr[4];
#pragma unroll
      for (int i = 0; i < 4; ++i) af[i] = *(const halfx8*)(&As[(wm + i * 16 + m15) * 64 + ko]);
#pragma unroll
      for (int j = 0; j < 4; ++j) bfr[j] = *(const halfx8*)(&Bs[(wn + j * 16 + m15) * 64 + ko]);
#pragma unroll
      for (int i = 0; i < 4; ++i)
#pragma unroll
        for (int j = 0; j < 4; ++j) acc[i][j] = mfma16(af[i], bfr[j], acc[i][j]);
    }
  }
#pragma unroll
  for (int j = 0; j < 4; ++j) {
    const int n = colBase + wn + j * 16 + m15;
    const float bv = bias[n];
#pragma unroll
    for (int i = 0; i < 4; ++i)
#pragma unroll
      for (int r = 0; r < 4; ++r) {
        const int m = rowBase + wm + i * 16 + q * 4 + r;
        C[(size_t)m * N + n] = fmaxf(acc[i][j][r] + bv, 0.f);
      }
  }
}

// ---------------- fused persistent GRU (2 layers) + FC + softmax ----------------
// 256 blocks x 1024 thr (16 waves), 1 block/CU. Block owns 32 batch rows for all 128
// steps. Wave w owns gate-col tile [w*16, w*16+16) for all 3 gates of both matmuls.
// Weights pre-repacked to B-frag order -> coalesced 1KB loads, L2-resident.
// h triple-buffered in LDS (fp16); fp32 z*h passthrough in registers.
// launch_bounds(1024,4): grid==256 means exactly 1 block/CU, so allow the full
// 128-VGPR budget (at 64 the unrolled weight loads can't stay in flight).
// FC+softmax fused into waves 14/15 (one 16-row tile each, 3 col tiles, in-wave
// shfl reduction) -> no lg LDS buffer, no third barrier, softmax overlaps next L0.
#define HLD 260  // padded LDS row stride in halves (130 dwords; 130%32=2 -> even bank spread)

template <bool SKIPH>
__device__ __forceinline__ void gru_layer(
    const half_t* __restrict__ X, const half_t* __restrict__ Hold, half_t* __restrict__ Hnew,
    const half_t* __restrict__ wip, const half_t* __restrict__ whp,  // repacked
    const float* __restrict__ bl, float (&hold)[2][4],
    const int w, const int q, const int m15, const int lane) {
  const floatx4 z4 = {0.f, 0.f, 0.f, 0.f};
  floatx4 accR[2] = {z4, z4}, accZ[2] = {z4, z4}, accNi[2] = {z4, z4}, accNh[2] = {z4, z4};
  // weight frag element offset: ((g*16 + w)*8 + ks)*64*8 + lane*8 ; g stride = 65536 elems
  const half_t* bi = wip + ((size_t)w * 8 * 64 + lane) * 8;
  const half_t* bh = whp + ((size_t)w * 8 * 64 + lane) * 8;
#pragma unroll
  for (int ks = 0; ks < 8; ++ks) {
    const int ko = ks * 32 + q * 8;
    const int fo = ks * 512;  // 64 lanes * 8 elems
    halfx8 x0 = *(const halfx8*)(&X[m15 * HLD + ko]);
    halfx8 x1 = *(const halfx8*)(&X[(16 + m15) * HLD + ko]);
    halfx8 wr = *(const halfx8*)(bi + fo);
    halfx8 wz = *(const halfx8*)(bi + 65536 + fo);
    halfx8 wn = *(const halfx8*)(bi + 131072 + fo);
    accR[0] = mfma16(x0, wr, accR[0]);  accR[1] = mfma16(x1, wr, accR[1]);
    accZ[0] = mfma16(x0, wz, accZ[0]);  accZ[1] = mfma16(x1, wz, accZ[1]);
    accNi[0] = mfma16(x0, wn, accNi[0]); accNi[1] = mfma16(x1, wn, accNi[1]);
    if (!SKIPH) {
      halfx8 h0 = *(const halfx8*)(&Hold[m15 * HLD + ko]);
      halfx8 h1 = *(const halfx8*)(&Hold[(16 + m15) * HLD + ko]);
      halfx8 vr = *(const halfx8*)(bh + fo);
      halfx8 vz = *(const halfx8*)(bh + 65536 + fo);
      halfx8 vn = *(const halfx8*)(bh + 131072 + fo);
      accR[0] = mfma16(h0, vr, accR[0]);  accR[1] = mfma16(h1, vr, accR[1]);
      accZ[0] = mfma16(h0, vz, accZ[0]);  accZ[1] = mfma16(h1, vz, accZ[1]);
      accNh[0] = mfma16(h0, vn, accNh[0]); accNh[1] = mfma16(h1, vn, accNh[1]);
    }
  }
  const int col = w * 16 + m15;
  const float br = bl[col], bz = bl[256 + col], bin = bl[512 + col], bhn = bl[768 + col];
#pragma unroll
  for (int mt = 0; mt < 2; ++mt)
#pragma unroll
    for (int r = 0; r < 4; ++r) {
      const float rr = sigmoidf_(accR[mt][r] + br);
      const float zz = sigmoidf_(accZ[mt][r] + bz);
      const float nn = tanhf_(accNi[mt][r] + bin + rr * (accNh[mt][r] + bhn));
      float hv = hold[mt][r];
      hv = (1.f - zz) * nn + zz * hv;
      hold[mt][r] = hv;
      Hnew[(mt * 16 + q * 4 + r) * HLD + col] = (half_t)hv;
    }
  __syncthreads();
}

__global__ __launch_bounds__(1024, 4) void gru_fused(
    const float* __restrict__ e,
    const half_t* __restrict__ wih0, const half_t* __restrict__ whh0,
    const half_t* __restrict__ wih1, const half_t* __restrict__ whh1,
    const float* __restrict__ bih0, const float* __restrict__ bhh0,
    const float* __restrict__ bih1, const float* __restrict__ bhh1,
    const half_t* __restrict__ wfc, const float* __restrict__ bfc,
    float* __restrict__ out) {
  __shared__ half_t hbuf[3][32 * HLD];
  __shared__ float bL[2][1024];  // [layer][{r_sum, z_sum, n_ih, n_hh} x 256]
  const int t = threadIdx.x;
  const int w = t >> 6, lane = t & 63;
  const int q = lane >> 4, m15 = lane & 15;
  const int rowBase = blockIdx.x * 32;

  for (int i = t; i < 2048; i += 1024) {
    const int layer = i >> 10, rem = i & 1023;
    const int which = rem >> 8, c = rem & 255;
    const float* bi = layer ? bih1 : bih0;
    const float* bh = layer ? bhh1 : bhh0;
    float v;
    if (which == 0) v = bi[c] + bh[c];
    else if (which == 1) v = bi[256 + c] + bh[256 + c];
    else if (which == 2) v = bi[512 + c];
    else v = bh[512 + c];
    bL[layer][rem] = v;
  }
  for (int i = t; i < 32 * 256; i += 1024) {
    const int r = i >> 8, c = i & 255;
    hbuf[0][r * HLD + c] = (half_t)e[(size_t)(rowBase + r) * 256 + c];  // xt(0)
  }
  __syncthreads();

  float h0old[2][4] = {};
  float h1old[2][4] = {};

  // rotating buffers: pX1 = h1_old (= x_t), pX0 = h0_old, pF = free
  half_t* pX1 = hbuf[0];
  half_t* pX0 = hbuf[1];
  half_t* pF  = hbuf[2];

#pragma unroll 1
  for (int ts = 0; ts < 128; ++ts) {
    if (ts == 0) {
      gru_layer<true >(pX1, pX0, pF,  wih0, whh0, bL[0], h0old, w, q, m15, lane);
      gru_layer<true >(pF,  pX1, pX0, wih1, whh1, bL[1], h1old, w, q, m15, lane);
    } else {
      gru_layer<false>(pX1, pX0, pF,  wih0, whh0, bL[0], h0old, w, q, m15, lane);
      gru_layer<false>(pF,  pX1, pX0, wih1, whh1, bL[1], h1old, w, q, m15, lane);
    }
    // h1_new now in pX0 buffer; h0_new in pF buffer.
    // ---- fused FC + softmax: waves 14,15 only (mt = w-14 row tile) ----
    // No barrier needed: FC reads pX0, first overwrite of that buffer is
    // L0(ts+2), which is >=2 barriers after these reads. Other 14 waves
    // proceed directly into the next step's layer 0.
    if (w >= 14) {
      const int mt = w - 14;
      const floatx4 z4 = {0.f, 0.f, 0.f, 0.f};
      floatx4 a3[3] = {z4, z4, z4};
#pragma unroll
      for (int ks = 0; ks < 8; ++ks) {
        const int ko = ks * 32 + q * 8;
        const halfx8 hf = *(const halfx8*)(&pX0[(mt * 16 + m15) * HLD + ko]);
#pragma unroll
        for (int c = 0; c < 3; ++c) {
          const halfx8 wf = *(const halfx8*)(wfc + ((size_t)(c * 8 + ks) * 64 + lane) * 8);
          a3[c] = mfma16(hf, wf, a3[c]);
        }
      }
      float v[3][4];
#pragma unroll
      for (int c = 0; c < 3; ++c) {
        const int col = c * 16 + m15;
        const bool ok = col < 42;
        const float bv = ok ? bfc[col] : 0.f;
#pragma unroll
        for (int r = 0; r < 4; ++r)
          v[c][r] = ok ? fmaxf(a3[c][r] + bv, 0.f) : -1e30f;
      }
      // per-row softmax: row (q,r) lives in the 16 lanes of this q-group, 3 regs each
#pragma unroll
      for (int r = 0; r < 4; ++r) {
        float mx = fmaxf(fmaxf(v[0][r], v[1][r]), v[2][r]);
#pragma unroll
        for (int d = 1; d < 16; d <<= 1) mx = fmaxf(mx, __shfl_xor(mx, d, 16));
        float ex[3]; float sm = 0.f;
#pragma unroll
        for (int c = 0; c < 3; ++c) { ex[c] = __expf(v[c][r] - mx); sm += ex[c]; }
#pragma unroll
        for (int d = 1; d < 16; d <<= 1) sm += __shfl_xor(sm, d, 16);
        const float inv = 1.f / sm;
        const int row = mt * 16 + q * 4 + r;
        const size_t base = ((size_t)(rowBase + row) * 128 + ts) * 42;
#pragma unroll
        for (int c = 0; c < 3; ++c) {
          const int col = c * 16 + m15;
          if (col < 42) __builtin_nontemporal_store(ex[c] * inv, &out[base + col]);
        }
      }
    }
    // rotate: h1_old <- pX0 (h1_new), h0_old <- pF (h0_new), free <- pX1
    half_t* tmp = pX1; pX1 = pX0; pX0 = pF; pF = tmp;
  }
}

// ---------------- host launch ----------------
static inline void conv(const float* s, half_t* d, int sr, int sc, int dr, int dc,
                        hipStream_t st) {
  int total = dr * dc;
  int blocks = (total + 255) / 256;
  if (blocks > 4096) blocks = 4096;
  convert_pad<<<blocks, 256, 0, st>>>(s, d, sr, sc, dr, dc);
}

static inline void repk(const float* s, half_t* d, int ntCount, int srcRows, hipStream_t st) {
  int total = ntCount * 8 * 64 * 8;
  int blocks = (total + 255) / 256;
  repack_bfrag<<<blocks, 256, 0, st>>>(s, d, ntCount, srcRows);
}

extern "C" void kernel_launch(void* const* d_in, const int* in_sizes, int n_in,
                              void* d_out, int out_size, void* d_ws, size_t ws_size,
                              hipStream_t stream) {
  const float* x    = (const float*)d_in[0];
  const float* w1   = (const float*)d_in[1];
  const float* b1   = (const float*)d_in[2];
  const float* w2   = (const float*)d_in[3];
  const float* b2   = (const float*)d_in[4];
  const float* w3   = (const float*)d_in[5];
  const float* b3   = (const float*)d_in[6];
  const float* w4   = (const float*)d_in[7];
  const float* b4   = (const float*)d_in[8];
  const float* wih0 = (const float*)d_in[9];
  const float* whh0 = (const float*)d_in[10];
  const float* bih0 = (const float*)d_in[11];
  const float* bhh0 = (const float*)d_in[12];
  const float* wih1 = (const float*)d_in[13];
  const float* whh1 = (const float*)d_in[14];
  const float* bih1 = (const float*)d_in[15];
  const float* bhh1 = (const float*)d_in[16];
  const float* wfc  = (const float*)d_in[17];
  const float* bfc  = (const float*)d_in[18];

  char* p = (char*)d_ws;
  half_t* w1b  = (half_t*)p; p += (size_t)2048 * 4864 * 2;
  half_t* w2b  = (half_t*)p; p += (size_t)1024 * 2048 * 2;
  half_t* w3b  = (half_t*)p; p += (size_t)512 * 1024 * 2;
  half_t* w4b  = (half_t*)p; p += (size_t)256 * 512 * 2;
  half_t* wi0b = (half_t*)p; p += (size_t)48 * 4096 * 2;   // repacked B-frag order
  half_t* wh0b = (half_t*)p; p += (size_t)48 * 4096 * 2;
  half_t* wi1b = (half_t*)p; p += (size_t)48 * 4096 * 2;
  half_t* wh1b = (half_t*)p; p += (size_t)48 * 4096 * 2;
  half_t* wfcb = (half_t*)p; p += (size_t)3 * 4096 * 2;
  float* e1 = (float*)p; p += (size_t)8192 * 2048 * 4;
  float* e2 = (float*)p; p += (size_t)8192 * 1024 * 4;
  float* e3 = (float*)p; p += (size_t)8192 * 512 * 4;
  float* e4 = (float*)p; p += (size_t)8192 * 256 * 4;

  conv(w1, w1b, 2048, 4860, 2048, 4864, stream);
  conv(w2, w2b, 1024, 2048, 1024, 2048, stream);
  conv(w3, w3b, 512, 1024, 512, 1024, stream);
  conv(w4, w4b, 256, 512, 256, 512, stream);
  repk(wih0, wi0b, 48, 768, stream);
  repk(whh0, wh0b, 48, 768, stream);
  repk(wih1, wi1b, 48, 768, stream);
  repk(whh1, wh1b, 48, 768, stream);
  repk(wfc, wfcb, 3, 42, stream);

  gemm_bias_relu<<<dim3(64, 16), 256, 0, stream>>>(x, 4860, 4860, w1b, 4864, b1, e1, 2048, 4864);
  gemm_bias_relu<<<dim3(64, 8),  256, 0, stream>>>(e1, 2048, 2048, w2b, 2048, b2, e2, 1024, 2048);
  gemm_bias_relu<<<dim3(64, 4),  256, 0, stream>>>(e2, 1024, 1024, w3b, 1024, b3, e3, 512, 1024);
  gemm_bias_relu<<<dim3(64, 2),  256, 0, stream>>>(e3, 512, 512, w4b, 512, b4, e4, 256, 512);

  gru_fused<<<256, 1024, 0, stream>>>(e4, wi0b, wh0b, wi1b, wh1b,
                                      bih0, bhh0, bih1, bhh1, wfcb, bfc, (float*)d_out);
}

// Round 2
// 7676.805 us; speedup vs baseline: 1.0931x; 1.0931x over previous
//
#include <hip/hip_runtime.h>
#include <stdint.h>
#include <stddef.h>

typedef _Float16 half_t;
typedef __attribute__((ext_vector_type(8))) _Float16 halfx8;
typedef __attribute__((ext_vector_type(4))) float floatx4;

__device__ __forceinline__ float sigmoidf_(float x) { return 1.f / (1.f + __expf(-x)); }
__device__ __forceinline__ float tanhf_(float x) {
  x = fminf(fmaxf(x, -15.f), 15.f);
  float e = __expf(2.f * x);
  return (e - 1.f) / (e + 1.f);
}

__device__ __forceinline__ floatx4 mfma16(halfx8 a, halfx8 b, floatx4 c) {
  return __builtin_amdgcn_mfma_f32_16x16x32_f16(a, b, c, 0, 0, 0);
}

// ---------------- fp32 -> fp16 convert with optional row/col zero-pad ----------------
__global__ void convert_pad(const float* __restrict__ src, half_t* __restrict__ dst,
                            int srcRows, int srcCols, int dstRows, int dstCols) {
  int total = dstRows * dstCols;
  for (int i = blockIdx.x * blockDim.x + threadIdx.x; i < total; i += gridDim.x * blockDim.x) {
    int r = i / dstCols, c = i - r * dstCols;
    float v = (r < srcRows && c < srcCols) ? src[(size_t)r * srcCols + c] : 0.f;
    dst[i] = (half_t)v;
  }
}

// ---------------- repack W (rows x 256, fp32) into MFMA B-frag order -------------------
// dst[nt][ks][lane][j] = W[nt*16 + (lane&15)][ks*32 + (lane>>4)*8 + j], fp16.
// (used for the small FC weight)
__global__ void repack_bfrag(const float* __restrict__ src, half_t* __restrict__ dst,
                             int ntCount, int srcRows) {
  int total = ntCount * 8 * 64 * 8;
  for (int i = blockIdx.x * blockDim.x + threadIdx.x; i < total; i += gridDim.x * blockDim.x) {
    int j = i & 7, lane = (i >> 3) & 63, ks = (i >> 9) & 7, nt = i >> 12;
    int q = lane >> 4, m15 = lane & 15;
    int row = nt * 16 + m15;
    int col = ks * 32 + q * 8 + j;
    float v = (row < srcRows) ? src[(size_t)row * 256 + col] : 0.f;
    dst[i] = (half_t)v;
  }
}

// ---------------- repack GRU W (768 x 256, fp32) gate-contiguous B-frag order ----------
// dst[((w*8+ks)*64 + lane)*24 + g*8 + j] = W[g*256 + w*16 + (lane&15)][ks*32 + (lane>>4)*8 + j]
// Per (wave,ks): 64 lanes x 24 halves = one contiguous 3KB chunk; per lane the three
// gate fragments sit at +0/+16/+32 BYTES from one base -> 3 dwordx4 loads off one
// address register with immediate offsets (frees VGPRs for the prefetch pipeline).
__global__ void repack_bfrag3(const float* __restrict__ src, half_t* __restrict__ dst,
                              int wCount) {
  int total = wCount * 8 * 64 * 24;
  for (int i = blockIdx.x * blockDim.x + threadIdx.x; i < total; i += gridDim.x * blockDim.x) {
    int j = i & 7;
    int g = (i >> 3) % 3;
    int rest = i / 24;          // lane + 64*ks + 512*w
    int lane = rest & 63;
    int ks = (rest >> 6) & 7;
    int w = rest >> 9;
    int q = lane >> 4, m15 = lane & 15;
    int row = g * 256 + w * 16 + m15;
    int col = ks * 32 + q * 8 + j;
    dst[i] = (half_t)src[(size_t)row * 256 + col];
  }
}

// ---------------- GEMM: C(MxN,fp32) = relu(A(MxKa,fp32) * B(NxKp,fp16)^T + bias) ------
__global__ __launch_bounds__(256) void gemm_bias_relu(
    const float* __restrict__ A, int lda, int Ka,
    const half_t* __restrict__ B, int ldb,
    const float* __restrict__ bias,
    float* __restrict__ C, int N, int Kp) {
  __shared__ half_t As[128 * 64];
  __shared__ half_t Bs[128 * 64];
  const int t = threadIdx.x;
  const int w = t >> 6, l = t & 63;
  const int q = l >> 4, m15 = l & 15;
  const int rowBase = blockIdx.x * 128, colBase = blockIdx.y * 128;
  const int wm = (w >> 1) * 64, wn = (w & 1) * 64;
  const floatx4 z4 = {0.f, 0.f, 0.f, 0.f};
  floatx4 acc[4][4];
#pragma unroll
  for (int i = 0; i < 4; ++i)
#pragma unroll
    for (int j = 0; j < 4; ++j) acc[i][j] = z4;

  const int sr = t >> 3;
  const int sc = (t & 7) * 8;

  for (int k0 = 0; k0 < Kp; k0 += 64) {
    __syncthreads();
    const bool full = (k0 + 64 <= Ka);
#pragma unroll
    for (int p = 0; p < 4; ++p) {
      const int r = p * 32 + sr;
      halfx8 tmp;
      if (full) {
        const float4* s0 = (const float4*)(A + (size_t)(rowBase + r) * lda + k0 + sc);
        float4 f0 = s0[0], f1 = s0[1];
        tmp[0] = (half_t)f0.x; tmp[1] = (half_t)f0.y; tmp[2] = (half_t)f0.z; tmp[3] = (half_t)f0.w;
        tmp[4] = (half_t)f1.x; tmp[5] = (half_t)f1.y; tmp[6] = (half_t)f1.z; tmp[7] = (half_t)f1.w;
      } else {
#pragma unroll
        for (int j2 = 0; j2 < 8; ++j2) {
          int kk = k0 + sc + j2;
          tmp[j2] = (half_t)(kk < Ka ? A[(size_t)(rowBase + r) * lda + kk] : 0.f);
        }
      }
      *(halfx8*)(&As[r * 64 + sc]) = tmp;
    }
#pragma unroll
    for (int p = 0; p < 4; ++p) {
      const int chunk = p * 256 + t;
      const int r = chunk >> 3, cc = (chunk & 7) * 8;
      *(halfx8*)(&Bs[r * 64 + cc]) =
          *(const halfx8*)(B + (size_t)(colBase + r) * ldb + k0 + cc);
    }
    __syncthreads();
#pragma unroll
    for (int kk = 0; kk < 2; ++kk) {
      const int ko = kk * 32 + q * 8;
      halfx8 af[4], bfr[4];
#pragma unroll
      for (int i = 0; i < 4; ++i) af[i] = *(const halfx8*)(&As[(wm + i * 16 + m15) * 64 + ko]);
#pragma unroll
      for (int j = 0; j < 4; ++j) bfr[j] = *(const halfx8*)(&Bs[(wn + j * 16 + m15) * 64 + ko]);
#pragma unroll
      for (int i = 0; i < 4; ++i)
#pragma unroll
        for (int j = 0; j < 4; ++j) acc[i][j] = mfma16(af[i], bfr[j], acc[i][j]);
    }
  }
#pragma unroll
  for (int j = 0; j < 4; ++j) {
    const int n = colBase + wn + j * 16 + m15;
    const float bv = bias[n];
#pragma unroll
    for (int i = 0; i < 4; ++i)
#pragma unroll
      for (int r = 0; r < 4; ++r) {
        const int m = rowBase + wm + i * 16 + q * 4 + r;
        C[(size_t)m * N + n] = fmaxf(acc[i][j][r] + bv, 0.f);
      }
  }
}

// ---------------- fused persistent GRU (2 layers) + FC + softmax ----------------
// 256 blocks x 1024 thr (16 waves), 1 block/CU. Block owns 32 batch rows for all 128
// steps. Wave w owns gate-col tile [w*16, w*16+16) for all 3 gates of both matmuls.
// Weight fragments are software-pipelined one ks iteration ahead (cur/nxt register
// sets): at 64 VGPRs one iteration's operands (24 frag + 32 acc + 16 LDS + addr) can't
// coexist, forcing serial load-waits; the explicit pipeline pushes allocation toward
// the 128-VGPR ceiling (4 waves/EU) and makes each iteration's MFMAs depend only on
// loads issued a full iteration earlier.
#define HLD 260  // padded LDS row stride in halves (130 dwords; 130%32=2 -> even bank spread)

template <bool SKIPH>
__device__ __forceinline__ void gru_layer(
    const half_t* __restrict__ X, const half_t* __restrict__ Hold, half_t* __restrict__ Hnew,
    const half_t* __restrict__ wip, const half_t* __restrict__ whp,  // gate-contiguous repack
    const float* __restrict__ bl, float (&hold)[2][4],
    const int w, const int q, const int m15, const int lane) {
  const floatx4 z4 = {0.f, 0.f, 0.f, 0.f};
  floatx4 accR[2] = {z4, z4}, accZ[2] = {z4, z4}, accNi[2] = {z4, z4}, accNh[2] = {z4, z4};
  // per-(wave,ks) 3KB chunk: base + ks*1536 elems; lane base = +lane*24; gates at +0/+8/+16
  const half_t* bi = wip + ((size_t)(w * 8) * 64 + lane) * 24;
  const half_t* bh = whp + ((size_t)(w * 8) * 64 + lane) * 24;
  // prologue: ks=0 fragments
  halfx8 cwr = *(const halfx8*)(bi);
  halfx8 cwz = *(const halfx8*)(bi + 8);
  halfx8 cwn = *(const halfx8*)(bi + 16);
  halfx8 cvr, cvz, cvn;
  if (!SKIPH) {
    cvr = *(const halfx8*)(bh);
    cvz = *(const halfx8*)(bh + 8);
    cvn = *(const halfx8*)(bh + 16);
  }
#pragma unroll
  for (int ks = 0; ks < 8; ++ks) {
    const int ko = ks * 32 + q * 8;
    halfx8 nwr, nwz, nwn, nvr, nvz, nvn;
    if (ks < 7) {  // issue next-iteration weight loads before this iteration's MFMAs
      const half_t* pi = bi + (ks + 1) * 1536;
      nwr = *(const halfx8*)(pi);
      nwz = *(const halfx8*)(pi + 8);
      nwn = *(const halfx8*)(pi + 16);
      if (!SKIPH) {
        const half_t* ph = bh + (ks + 1) * 1536;
        nvr = *(const halfx8*)(ph);
        nvz = *(const halfx8*)(ph + 8);
        nvn = *(const halfx8*)(ph + 16);
      }
    }
    {
      halfx8 x0 = *(const halfx8*)(&X[m15 * HLD + ko]);
      accR[0] = mfma16(x0, cwr, accR[0]);
      accZ[0] = mfma16(x0, cwz, accZ[0]);
      accNi[0] = mfma16(x0, cwn, accNi[0]);
    }
    {
      halfx8 x1 = *(const halfx8*)(&X[(16 + m15) * HLD + ko]);
      accR[1] = mfma16(x1, cwr, accR[1]);
      accZ[1] = mfma16(x1, cwz, accZ[1]);
      accNi[1] = mfma16(x1, cwn, accNi[1]);
    }
    if (!SKIPH) {
      {
        halfx8 h0 = *(const halfx8*)(&Hold[m15 * HLD + ko]);
        accR[0] = mfma16(h0, cvr, accR[0]);
        accZ[0] = mfma16(h0, cvz, accZ[0]);
        accNh[0] = mfma16(h0, cvn, accNh[0]);
      }
      {
        halfx8 h1 = *(const halfx8*)(&Hold[(16 + m15) * HLD + ko]);
        accR[1] = mfma16(h1, cvr, accR[1]);
        accZ[1] = mfma16(h1, cvz, accZ[1]);
        accNh[1] = mfma16(h1, cvn, accNh[1]);
      }
    }
    if (ks < 7) {
      cwr = nwr; cwz = nwz; cwn = nwn;
      if (!SKIPH) { cvr = nvr; cvz = nvz; cvn = nvn; }
    }
  }
  const int col = w * 16 + m15;
  const float br = bl[col], bz = bl[256 + col], bin = bl[512 + col], bhn = bl[768 + col];
#pragma unroll
  for (int mt = 0; mt < 2; ++mt)
#pragma unroll
    for (int r = 0; r < 4; ++r) {
      const float rr = sigmoidf_(accR[mt][r] + br);
      const float zz = sigmoidf_(accZ[mt][r] + bz);
      const float nn = tanhf_(accNi[mt][r] + bin + rr * (accNh[mt][r] + bhn));
      float hv = hold[mt][r];
      hv = (1.f - zz) * nn + zz * hv;
      hold[mt][r] = hv;
      Hnew[(mt * 16 + q * 4 + r) * HLD + col] = (half_t)hv;
    }
  __syncthreads();
}

__global__ __launch_bounds__(1024, 4) void gru_fused(
    const float* __restrict__ e,
    const half_t* __restrict__ wih0, const half_t* __restrict__ whh0,
    const half_t* __restrict__ wih1, const half_t* __restrict__ whh1,
    const float* __restrict__ bih0, const float* __restrict__ bhh0,
    const float* __restrict__ bih1, const float* __restrict__ bhh1,
    const half_t* __restrict__ wfc, const float* __restrict__ bfc,
    float* __restrict__ out) {
  __shared__ half_t hbuf[3][32 * HLD];
  __shared__ float lg[32 * 48];
  __shared__ float bL[2][1024];  // [layer][{r_sum, z_sum, n_ih, n_hh} x 256]
  const int t = threadIdx.x;
  const int w = t >> 6, lane = t & 63;
  const int q = lane >> 4, m15 = lane & 15;
  const int rowBase = blockIdx.x * 32;

  for (int i = t; i < 2048; i += 1024) {
    const int layer = i >> 10, rem = i & 1023;
    const int which = rem >> 8, c = rem & 255;
    const float* bi = layer ? bih1 : bih0;
    const float* bh = layer ? bhh1 : bhh0;
    float v;
    if (which == 0) v = bi[c] + bh[c];
    else if (which == 1) v = bi[256 + c] + bh[256 + c];
    else if (which == 2) v = bi[512 + c];
    else v = bh[512 + c];
    bL[layer][rem] = v;
  }
  for (int i = t; i < 32 * 256; i += 1024) {
    const int r = i >> 8, c = i & 255;
    hbuf[0][r * HLD + c] = (half_t)e[(size_t)(rowBase + r) * 256 + c];  // xt(0)
  }
  __syncthreads();

  float h0old[2][4] = {};
  float h1old[2][4] = {};

  // rotating buffers: pX1 = h1_old (= x_t), pX0 = h0_old, pF = free
  half_t* pX1 = hbuf[0];
  half_t* pX0 = hbuf[1];
  half_t* pF  = hbuf[2];

#pragma unroll 1
  for (int ts = 0; ts < 128; ++ts) {
    if (ts == 0) {
      gru_layer<true >(pX1, pX0, pF,  wih0, whh0, bL[0], h0old, w, q, m15, lane);
      gru_layer<true >(pF,  pX1, pX0, wih1, whh1, bL[1], h1old, w, q, m15, lane);
    } else {
      gru_layer<false>(pX1, pX0, pF,  wih0, whh0, bL[0], h0old, w, q, m15, lane);
      gru_layer<false>(pF,  pX1, pX0, wih1, whh1, bL[1], h1old, w, q, m15, lane);
    }
    // h1_new now in pX0 buffer; h0_new in pF buffer.
    // ---- FC: y = relu(h1 @ wfc^T + bfc) -> lg ----
    if (w < 3) {
      const floatx4 z4 = {0.f, 0.f, 0.f, 0.f};
      floatx4 acc[2] = {z4, z4};
      const half_t* bw = wfc + ((size_t)w * 8 * 64 + lane) * 8;
#pragma unroll
      for (int ks = 0; ks < 8; ++ks) {
        const int ko = ks * 32 + q * 8;
        const halfx8 wf = *(const halfx8*)(bw + ks * 512);
#pragma unroll
        for (int mt = 0; mt < 2; ++mt) {
          const halfx8 hf = *(const halfx8*)(&pX0[(mt * 16 + m15) * HLD + ko]);
          acc[mt] = mfma16(hf, wf, acc[mt]);
        }
      }
      const int col = w * 16 + m15;
      const float bv = (col < 42) ? bfc[col] : 0.f;
#pragma unroll
      for (int mt = 0; mt < 2; ++mt)
#pragma unroll
        for (int r = 0; r < 4; ++r) {
          const int m = mt * 16 + q * 4 + r;
          lg[m * 48 + col] = (col < 42) ? fmaxf(acc[mt][r] + bv, 0.f) : -1e30f;
        }
    }
    __syncthreads();
    // ---- softmax over 42 classes + store (first 4 waves) ----
    if (t < 256) {
      const int row = t >> 3, s = t & 7;
      float v[6];
#pragma unroll
      for (int k2 = 0; k2 < 6; ++k2) v[k2] = lg[row * 48 + s + k2 * 8];
      float mx = v[0];
#pragma unroll
      for (int k2 = 1; k2 < 6; ++k2) mx = fmaxf(mx, v[k2]);
#pragma unroll
      for (int d = 1; d < 8; d <<= 1) mx = fmaxf(mx, __shfl_xor(mx, d, 8));
      float sm = 0.f;
#pragma unroll
      for (int k2 = 0; k2 < 6; ++k2) { v[k2] = __expf(v[k2] - mx); sm += v[k2]; }
#pragma unroll
      for (int d = 1; d < 8; d <<= 1) sm += __shfl_xor(sm, d, 8);
      const float inv = 1.f / sm;
      const size_t base = ((size_t)(rowBase + row) * 128 + ts) * 42;
#pragma unroll
      for (int k2 = 0; k2 < 6; ++k2) {
        const int col = s + k2 * 8;
        if (col < 42) __builtin_nontemporal_store(v[k2] * inv, &out[base + col]);
      }
    }
    // rotate: h1_old <- pX0 (h1_new), h0_old <- pF (h0_new), free <- pX1
    half_t* tmp = pX1; pX1 = pX0; pX0 = pF; pF = tmp;
    // no trailing barrier: next writes to lg / h-bufs are >=1 full barrier away
  }
}

// ---------------- host launch ----------------
static inline void conv(const float* s, half_t* d, int sr, int sc, int dr, int dc,
                        hipStream_t st) {
  int total = dr * dc;
  int blocks = (total + 255) / 256;
  if (blocks > 4096) blocks = 4096;
  convert_pad<<<blocks, 256, 0, st>>>(s, d, sr, sc, dr, dc);
}

static inline void repk(const float* s, half_t* d, int ntCount, int srcRows, hipStream_t st) {
  int total = ntCount * 8 * 64 * 8;
  int blocks = (total + 255) / 256;
  repack_bfrag<<<blocks, 256, 0, st>>>(s, d, ntCount, srcRows);
}

static inline void repk3(const float* s, half_t* d, hipStream_t st) {
  int total = 16 * 8 * 64 * 24;
  int blocks = (total + 255) / 256;
  repack_bfrag3<<<blocks, 256, 0, st>>>(s, d, 16);
}

extern "C" void kernel_launch(void* const* d_in, const int* in_sizes, int n_in,
                              void* d_out, int out_size, void* d_ws, size_t ws_size,
                              hipStream_t stream) {
  const float* x    = (const float*)d_in[0];
  const float* w1   = (const float*)d_in[1];
  const float* b1   = (const float*)d_in[2];
  const float* w2   = (const float*)d_in[3];
  const float* b2   = (const float*)d_in[4];
  const float* w3   = (const float*)d_in[5];
  const float* b3   = (const float*)d_in[6];
  const float* w4   = (const float*)d_in[7];
  const float* b4   = (const float*)d_in[8];
  const float* wih0 = (const float*)d_in[9];
  const float* whh0 = (const float*)d_in[10];
  const float* bih0 = (const float*)d_in[11];
  const float* bhh0 = (const float*)d_in[12];
  const float* wih1 = (const float*)d_in[13];
  const float* whh1 = (const float*)d_in[14];
  const float* bih1 = (const float*)d_in[15];
  const float* bhh1 = (const float*)d_in[16];
  const float* wfc  = (const float*)d_in[17];
  const float* bfc  = (const float*)d_in[18];

  char* p = (char*)d_ws;
  half_t* w1b  = (half_t*)p; p += (size_t)2048 * 4864 * 2;
  half_t* w2b  = (half_t*)p; p += (size_t)1024 * 2048 * 2;
  half_t* w3b  = (half_t*)p; p += (size_t)512 * 1024 * 2;
  half_t* w4b  = (half_t*)p; p += (size_t)256 * 512 * 2;
  half_t* wi0b = (half_t*)p; p += (size_t)48 * 4096 * 2;   // gate-contiguous B-frag order
  half_t* wh0b = (half_t*)p; p += (size_t)48 * 4096 * 2;
  half_t* wi1b = (half_t*)p; p += (size_t)48 * 4096 * 2;
  half_t* wh1b = (half_t*)p; p += (size_t)48 * 4096 * 2;
  half_t* wfcb = (half_t*)p; p += (size_t)3 * 4096 * 2;
  float* e1 = (float*)p; p += (size_t)8192 * 2048 * 4;
  float* e2 = (float*)p; p += (size_t)8192 * 1024 * 4;
  float* e3 = (float*)p; p += (size_t)8192 * 512 * 4;
  float* e4 = (float*)p; p += (size_t)8192 * 256 * 4;

  conv(w1, w1b, 2048, 4860, 2048, 4864, stream);
  conv(w2, w2b, 1024, 2048, 1024, 2048, stream);
  conv(w3, w3b, 512, 1024, 512, 1024, stream);
  conv(w4, w4b, 256, 512, 256, 512, stream);
  repk3(wih0, wi0b, stream);
  repk3(whh0, wh0b, stream);
  repk3(wih1, wi1b, stream);
  repk3(whh1, wh1b, stream);
  repk(wfc, wfcb, 3, 42, stream);

  gemm_bias_relu<<<dim3(64, 16), 256, 0, stream>>>(x, 4860, 4860, w1b, 4864, b1, e1, 2048, 4864);
  gemm_bias_relu<<<dim3(64, 8),  256, 0, stream>>>(e1, 2048, 2048, w2b, 2048, b2, e2, 1024, 2048);
  gemm_bias_relu<<<dim3(64, 4),  256, 0, stream>>>(e2, 1024, 1024, w3b, 1024, b3, e3, 512, 1024);
  gemm_bias_relu<<<dim3(64, 2),  256, 0, stream>>>(e3, 512, 512, w4b, 512, b4, e4, 256, 512);

  gru_fused<<<256, 1024, 0, stream>>>(e4, wi0b, wh0b, wi1b, wh1b,
                                      bih0, bhh0, bih1, bhh1, wfcb, bfc, (float*)d_out);
}

// Round 3
// 6069.817 us; speedup vs baseline: 1.3825x; 1.2648x over previous
//
#include <hip/hip_runtime.h>
#include <stdint.h>
#include <stddef.h>

typedef _Float16 half_t;
typedef __attribute__((ext_vector_type(8))) _Float16 halfx8;
typedef __attribute__((ext_vector_type(4))) float floatx4;

__device__ __forceinline__ float sigmoidf_(float x) { return 1.f / (1.f + __expf(-x)); }
__device__ __forceinline__ float tanhf_(float x) {
  x = fminf(fmaxf(x, -15.f), 15.f);
  float e = __expf(2.f * x);
  return (e - 1.f) / (e + 1.f);
}

__device__ __forceinline__ floatx4 mfma16(halfx8 a, halfx8 b, floatx4 c) {
  return __builtin_amdgcn_mfma_f32_16x16x32_f16(a, b, c, 0, 0, 0);
}

// Counted-vmcnt waits (T4): sched_barrier(0) after the wait is REQUIRED -- the
// "memory" clobber does not stop register-only MFMAs from hoisting above it.
__device__ __forceinline__ void waitv6() {
  asm volatile("s_waitcnt vmcnt(6)" ::: "memory");
  __builtin_amdgcn_sched_barrier(0);
}
__device__ __forceinline__ void waitv3() {
  asm volatile("s_waitcnt vmcnt(3)" ::: "memory");
  __builtin_amdgcn_sched_barrier(0);
}
__device__ __forceinline__ void waitv0() {
  asm volatile("s_waitcnt vmcnt(0)" ::: "memory");
  __builtin_amdgcn_sched_barrier(0);
}

// Three 16B weight-fragment loads off one base (gate-contiguous repack puts the
// three gates at +0/+16/+32 bytes). Inline asm so the compiler cannot re-serialize
// them: it does not track these loads, the counted waits above do.
#define GLOAD3(d0, d1, d2, p)                                          \
  asm volatile("global_load_dwordx4 %0, %3, off\n\t"                   \
               "global_load_dwordx4 %1, %3, off offset:16\n\t"         \
               "global_load_dwordx4 %2, %3, off offset:32"             \
               : "=&v"(d0), "=&v"(d1), "=&v"(d2)                       \
               : "v"(p)                                                \
               : "memory")

// ---------------- fp32 -> fp16 convert with optional row/col zero-pad ----------------
__global__ void convert_pad(const float* __restrict__ src, half_t* __restrict__ dst,
                            int srcRows, int srcCols, int dstRows, int dstCols) {
  int total = dstRows * dstCols;
  for (int i = blockIdx.x * blockDim.x + threadIdx.x; i < total; i += gridDim.x * blockDim.x) {
    int r = i / dstCols, c = i - r * dstCols;
    float v = (r < srcRows && c < srcCols) ? src[(size_t)r * srcCols + c] : 0.f;
    dst[i] = (half_t)v;
  }
}

// ---------------- repack W (rows x 256, fp32) into MFMA B-frag order -------------------
// dst[nt][ks][lane][j] = W[nt*16 + (lane&15)][ks*32 + (lane>>4)*8 + j], fp16.
// (used for the small FC weight)
__global__ void repack_bfrag(const float* __restrict__ src, half_t* __restrict__ dst,
                             int ntCount, int srcRows) {
  int total = ntCount * 8 * 64 * 8;
  for (int i = blockIdx.x * blockDim.x + threadIdx.x; i < total; i += gridDim.x * blockDim.x) {
    int j = i & 7, lane = (i >> 3) & 63, ks = (i >> 9) & 7, nt = i >> 12;
    int q = lane >> 4, m15 = lane & 15;
    int row = nt * 16 + m15;
    int col = ks * 32 + q * 8 + j;
    float v = (row < srcRows) ? src[(size_t)row * 256 + col] : 0.f;
    dst[i] = (half_t)v;
  }
}

// ---------------- repack GRU W (768 x 256, fp32) gate-contiguous B-frag order ----------
// dst[((w*8+ks)*64 + lane)*24 + g*8 + j] = W[g*256 + w*16 + (lane&15)][ks*32 + (lane>>4)*8 + j]
// Per lane the three gate fragments sit at +0/+16/+32 BYTES from one base.
__global__ void repack_bfrag3(const float* __restrict__ src, half_t* __restrict__ dst,
                              int wCount) {
  int total = wCount * 8 * 64 * 24;
  for (int i = blockIdx.x * blockDim.x + threadIdx.x; i < total; i += gridDim.x * blockDim.x) {
    int j = i & 7;
    int g = (i >> 3) % 3;
    int rest = i / 24;          // lane + 64*ks + 512*w
    int lane = rest & 63;
    int ks = (rest >> 6) & 7;
    int w = rest >> 9;
    int q = lane >> 4, m15 = lane & 15;
    int row = g * 256 + w * 16 + m15;
    int col = ks * 32 + q * 8 + j;
    dst[i] = (half_t)src[(size_t)row * 256 + col];
  }
}

// ---------------- GEMM: C(MxN,fp32) = relu(A(MxKa,fp32) * B(NxKp,fp16)^T + bias) ------
__global__ __launch_bounds__(256) void gemm_bias_relu(
    const float* __restrict__ A, int lda, int Ka,
    const half_t* __restrict__ B, int ldb,
    const float* __restrict__ bias,
    float* __restrict__ C, int N, int Kp) {
  __shared__ half_t As[128 * 64];
  __shared__ half_t Bs[128 * 64];
  const int t = threadIdx.x;
  const int w = t >> 6, l = t & 63;
  const int q = l >> 4, m15 = l & 15;
  const int rowBase = blockIdx.x * 128, colBase = blockIdx.y * 128;
  const int wm = (w >> 1) * 64, wn = (w & 1) * 64;
  const floatx4 z4 = {0.f, 0.f, 0.f, 0.f};
  floatx4 acc[4][4];
#pragma unroll
  for (int i = 0; i < 4; ++i)
#pragma unroll
    for (int j = 0; j < 4; ++j) acc[i][j] = z4;

  const int sr = t >> 3;
  const int sc = (t & 7) * 8;

  for (int k0 = 0; k0 < Kp; k0 += 64) {
    __syncthreads();
    const bool full = (k0 + 64 <= Ka);
#pragma unroll
    for (int p = 0; p < 4; ++p) {
      const int r = p * 32 + sr;
      halfx8 tmp;
      if (full) {
        const float4* s0 = (const float4*)(A + (size_t)(rowBase + r) * lda + k0 + sc);
        float4 f0 = s0[0], f1 = s0[1];
        tmp[0] = (half_t)f0.x; tmp[1] = (half_t)f0.y; tmp[2] = (half_t)f0.z; tmp[3] = (half_t)f0.w;
        tmp[4] = (half_t)f1.x; tmp[5] = (half_t)f1.y; tmp[6] = (half_t)f1.z; tmp[7] = (half_t)f1.w;
      } else {
#pragma unroll
        for (int j2 = 0; j2 < 8; ++j2) {
          int kk = k0 + sc + j2;
          tmp[j2] = (half_t)(kk < Ka ? A[(size_t)(rowBase + r) * lda + kk] : 0.f);
        }
      }
      *(halfx8*)(&As[r * 64 + sc]) = tmp;
    }
#pragma unroll
    for (int p = 0; p < 4; ++p) {
      const int chunk = p * 256 + t;
      const int r = chunk >> 3, cc = (chunk & 7) * 8;
      *(halfx8*)(&Bs[r * 64 + cc]) =
          *(const halfx8*)(B + (size_t)(colBase + r) * ldb + k0 + cc);
    }
    __syncthreads();
#pragma unroll
    for (int kk = 0; kk < 2; ++kk) {
      const int ko = kk * 32 + q * 8;
      halfx8 af[4], bfr[4];
#pragma unroll
      for (int i = 0; i < 4; ++i) af[i] = *(const halfx8*)(&As[(wm + i * 16 + m15) * 64 + ko]);
#pragma unroll
      for (int j = 0; j < 4; ++j) bfr[j] = *(const halfx8*)(&Bs[(wn + j * 16 + m15) * 64 + ko]);
#pragma unroll
      for (int i = 0; i < 4; ++i)
#pragma unroll
        for (int j = 0; j < 4; ++j) acc[i][j] = mfma16(af[i], bfr[j], acc[i][j]);
    }
  }
#pragma unroll
  for (int j = 0; j < 4; ++j) {
    const int n = colBase + wn + j * 16 + m15;
    const float bv = bias[n];
#pragma unroll
    for (int i = 0; i < 4; ++i)
#pragma unroll
      for (int r = 0; r < 4; ++r) {
        const int m = rowBase + wm + i * 16 + q * 4 + r;
        C[(size_t)m * N + n] = fmaxf(acc[i][j][r] + bv, 0.f);
      }
  }
}

// ---------------- fused persistent GRU (2 layers) + FC + softmax ----------------
// 256 blocks x 1024 thr (16 waves), 1 block/CU. Block owns 32 batch rows for all 128
// steps. Wave w owns gate-col tile [w*16, w*16+16) for all 3 gates of both matmuls.
// Weight loads are inline-asm global_load_dwordx4 in a 2-bank register ring with
// COUNTED s_waitcnt vmcnt(6) (T3/T4): bank A/B hold ks/ks+1; each half-iteration
// waits only for its own bank (the other stays in flight), runs 12 MFMAs, then
// reissues the consumed bank for ks+2. Drain to vmcnt(0) only at ks=7 so the
// compiler's pre-barrier drain finds nothing outstanding. No other global VMEM
// may sit inside the K-loop (biases live in per-thread registers).
#define HLD 260  // padded LDS row stride in halves

#define HALF_ITER(KS, W0, W1, W2, V0, V1, V2)                                    \
  {                                                                              \
    const int ko = (KS) * 32 + q * 8;                                            \
    halfx8 x0 = *(const halfx8*)(&X[m15 * HLD + ko]);                            \
    halfx8 x1 = *(const halfx8*)(&X[(16 + m15) * HLD + ko]);                     \
    halfx8 h0, h1;                                                               \
    if (!SKIPH) {                                                                \
      h0 = *(const halfx8*)(&Hold[m15 * HLD + ko]);                              \
      h1 = *(const halfx8*)(&Hold[(16 + m15) * HLD + ko]);                       \
    }                                                                            \
    if ((KS) == 7) waitv0(); else if (SKIPH) waitv3(); else waitv6();            \
    accR[0] = mfma16(x0, W0, accR[0]);   accR[1] = mfma16(x1, W0, accR[1]);      \
    accZ[0] = mfma16(x0, W1, accZ[0]);   accZ[1] = mfma16(x1, W1, accZ[1]);      \
    accNi[0] = mfma16(x0, W2, accNi[0]); accNi[1] = mfma16(x1, W2, accNi[1]);    \
    if (!SKIPH) {                                                                \
      accR[0] = mfma16(h0, V0, accR[0]);   accR[1] = mfma16(h1, V0, accR[1]);    \
      accZ[0] = mfma16(h0, V1, accZ[0]);   accZ[1] = mfma16(h1, V1, accZ[1]);    \
      accNh[0] = mfma16(h0, V2, accNh[0]); accNh[1] = mfma16(h1, V2, accNh[1]);  \
    }                                                                            \
    if ((KS) < 6) {                                                              \
      GLOAD3(W0, W1, W2, bi + ((KS) + 2) * 1536);                                \
      if (!SKIPH) { GLOAD3(V0, V1, V2, bh + ((KS) + 2) * 1536); }                \
    }                                                                            \
  }

template <bool SKIPH>
__device__ __forceinline__ void gru_layer(
    const half_t* __restrict__ X, const half_t* __restrict__ Hold, half_t* __restrict__ Hnew,
    const half_t* __restrict__ wip, const half_t* __restrict__ whp,  // gate-contiguous repack
    float br, float bz, float bin, float bhn, float (&hold)[2][4],
    const int w, const int q, const int m15, const int lane) {
  const floatx4 z4 = {0.f, 0.f, 0.f, 0.f};
  floatx4 accR[2] = {z4, z4}, accZ[2] = {z4, z4}, accNi[2] = {z4, z4}, accNh[2] = {z4, z4};
  // per-(wave,ks) 3KB chunk: base + ks*1536 elems; lane base = +lane*24; gates at +0/+16/+32 B
  const half_t* bi = wip + ((size_t)(w * 8) * 64 + lane) * 24;
  const half_t* bh = whp + ((size_t)(w * 8) * 64 + lane) * 24;

  halfx8 aw0, aw1, aw2, bw0, bw1, bw2;  // X-side weight banks A, B
  halfx8 av0, av1, av2, bv0, bv1, bv2;  // H-side weight banks A, B
  GLOAD3(aw0, aw1, aw2, bi);
  if (!SKIPH) { GLOAD3(av0, av1, av2, bh); }
  GLOAD3(bw0, bw1, bw2, bi + 1536);
  if (!SKIPH) { GLOAD3(bv0, bv1, bv2, bh + 1536); }

  HALF_ITER(0, aw0, aw1, aw2, av0, av1, av2)
  HALF_ITER(1, bw0, bw1, bw2, bv0, bv1, bv2)
  HALF_ITER(2, aw0, aw1, aw2, av0, av1, av2)
  HALF_ITER(3, bw0, bw1, bw2, bv0, bv1, bv2)
  HALF_ITER(4, aw0, aw1, aw2, av0, av1, av2)
  HALF_ITER(5, bw0, bw1, bw2, bv0, bv1, bv2)
  HALF_ITER(6, aw0, aw1, aw2, av0, av1, av2)
  HALF_ITER(7, bw0, bw1, bw2, bv0, bv1, bv2)

  const int col = w * 16 + m15;
#pragma unroll
  for (int mt = 0; mt < 2; ++mt)
#pragma unroll
    for (int r = 0; r < 4; ++r) {
      const float rr = sigmoidf_(accR[mt][r] + br);
      const float zz = sigmoidf_(accZ[mt][r] + bz);
      const float nn = tanhf_(accNi[mt][r] + bin + rr * (accNh[mt][r] + bhn));
      float hv = hold[mt][r];
      hv = (1.f - zz) * nn + zz * hv;
      hold[mt][r] = hv;
      Hnew[(mt * 16 + q * 4 + r) * HLD + col] = (half_t)hv;
    }
  __syncthreads();
}

__global__ __launch_bounds__(1024, 4) void gru_fused(
    const float* __restrict__ e,
    const half_t* __restrict__ wih0, const half_t* __restrict__ whh0,
    const half_t* __restrict__ wih1, const half_t* __restrict__ whh1,
    const float* __restrict__ bih0, const float* __restrict__ bhh0,
    const float* __restrict__ bih1, const float* __restrict__ bhh1,
    const half_t* __restrict__ wfc, const float* __restrict__ bfc,
    float* __restrict__ out) {
  __shared__ half_t hbuf[3][32 * HLD];
  __shared__ float lg[32 * 48];
  const int t = threadIdx.x;
  const int w = t >> 6, lane = t & 63;
  const int q = lane >> 4, m15 = lane & 15;
  const int rowBase = blockIdx.x * 32;

  // per-thread gate biases (keeps global VMEM out of the K-loop)
  const int bcol = w * 16 + m15;
  const float br0 = bih0[bcol] + bhh0[bcol];
  const float bz0 = bih0[256 + bcol] + bhh0[256 + bcol];
  const float bi0 = bih0[512 + bcol];
  const float bh0 = bhh0[512 + bcol];
  const float br1 = bih1[bcol] + bhh1[bcol];
  const float bz1 = bih1[256 + bcol] + bhh1[256 + bcol];
  const float bi1 = bih1[512 + bcol];
  const float bh1 = bhh1[512 + bcol];

  for (int i = t; i < 32 * 256; i += 1024) {
    const int r = i >> 8, c = i & 255;
    hbuf[0][r * HLD + c] = (half_t)e[(size_t)(rowBase + r) * 256 + c];  // xt(0)
  }
  __syncthreads();

  float h0old[2][4] = {};
  float h1old[2][4] = {};

  // rotating buffers: pX1 = h1_old (= x_t), pX0 = h0_old, pF = free
  half_t* pX1 = hbuf[0];
  half_t* pX0 = hbuf[1];
  half_t* pF  = hbuf[2];

#pragma unroll 1
  for (int ts = 0; ts < 128; ++ts) {
    if (ts == 0) {
      gru_layer<true >(pX1, pX0, pF,  wih0, whh0, br0, bz0, bi0, bh0, h0old, w, q, m15, lane);
      gru_layer<true >(pF,  pX1, pX0, wih1, whh1, br1, bz1, bi1, bh1, h1old, w, q, m15, lane);
    } else {
      gru_layer<false>(pX1, pX0, pF,  wih0, whh0, br0, bz0, bi0, bh0, h0old, w, q, m15, lane);
      gru_layer<false>(pF,  pX1, pX0, wih1, whh1, br1, bz1, bi1, bh1, h1old, w, q, m15, lane);
    }
    // h1_new now in pX0 buffer; h0_new in pF buffer.
    // ---- FC: y = relu(h1 @ wfc^T + bfc) -> lg ----
    if (w < 3) {
      const floatx4 z4 = {0.f, 0.f, 0.f, 0.f};
      floatx4 acc[2] = {z4, z4};
      const half_t* bw = wfc + ((size_t)w * 8 * 64 + lane) * 8;
#pragma unroll
      for (int ks = 0; ks < 8; ++ks) {
        const int ko = ks * 32 + q * 8;
        const halfx8 wf = *(const halfx8*)(bw + ks * 512);
#pragma unroll
        for (int mt = 0; mt < 2; ++mt) {
          const halfx8 hf = *(const halfx8*)(&pX0[(mt * 16 + m15) * HLD + ko]);
          acc[mt] = mfma16(hf, wf, acc[mt]);
        }
      }
      const int col = w * 16 + m15;
      const float bv = (col < 42) ? bfc[col] : 0.f;
#pragma unroll
      for (int mt = 0; mt < 2; ++mt)
#pragma unroll
        for (int r = 0; r < 4; ++r) {
          const int m = mt * 16 + q * 4 + r;
          lg[m * 48 + col] = (col < 42) ? fmaxf(acc[mt][r] + bv, 0.f) : -1e30f;
        }
    }
    __syncthreads();
    // ---- softmax over 42 classes + store (first 4 waves) ----
    if (t < 256) {
      const int row = t >> 3, s = t & 7;
      float v[6];
#pragma unroll
      for (int k2 = 0; k2 < 6; ++k2) v[k2] = lg[row * 48 + s + k2 * 8];
      float mx = v[0];
#pragma unroll
      for (int k2 = 1; k2 < 6; ++k2) mx = fmaxf(mx, v[k2]);
#pragma unroll
      for (int d = 1; d < 8; d <<= 1) mx = fmaxf(mx, __shfl_xor(mx, d, 8));
      float sm = 0.f;
#pragma unroll
      for (int k2 = 0; k2 < 6; ++k2) { v[k2] = __expf(v[k2] - mx); sm += v[k2]; }
#pragma unroll
      for (int d = 1; d < 8; d <<= 1) sm += __shfl_xor(sm, d, 8);
      const float inv = 1.f / sm;
      const size_t base = ((size_t)(rowBase + row) * 128 + ts) * 42;
#pragma unroll
      for (int k2 = 0; k2 < 6; ++k2) {
        const int col = s + k2 * 8;
        if (col < 42) __builtin_nontemporal_store(v[k2] * inv, &out[base + col]);
      }
    }
    // rotate: h1_old <- pX0 (h1_new), h0_old <- pF (h0_new), free <- pX1
    half_t* tmp = pX1; pX1 = pX0; pX0 = pF; pF = tmp;
    // no trailing barrier: next writes to lg / h-bufs are >=1 full barrier away
  }
}

// ---------------- host launch ----------------
static inline void conv(const float* s, half_t* d, int sr, int sc, int dr, int dc,
                        hipStream_t st) {
  int total = dr * dc;
  int blocks = (total + 255) / 256;
  if (blocks > 4096) blocks = 4096;
  convert_pad<<<blocks, 256, 0, st>>>(s, d, sr, sc, dr, dc);
}

static inline void repk(const float* s, half_t* d, int ntCount, int srcRows, hipStream_t st) {
  int total = ntCount * 8 * 64 * 8;
  int blocks = (total + 255) / 256;
  repack_bfrag<<<blocks, 256, 0, st>>>(s, d, ntCount, srcRows);
}

static inline void repk3(const float* s, half_t* d, hipStream_t st) {
  int total = 16 * 8 * 64 * 24;
  int blocks = (total + 255) / 256;
  repack_bfrag3<<<blocks, 256, 0, st>>>(s, d, 16);
}

extern "C" void kernel_launch(void* const* d_in, const int* in_sizes, int n_in,
                              void* d_out, int out_size, void* d_ws, size_t ws_size,
                              hipStream_t stream) {
  const float* x    = (const float*)d_in[0];
  const float* w1   = (const float*)d_in[1];
  const float* b1   = (const float*)d_in[2];
  const float* w2   = (const float*)d_in[3];
  const float* b2   = (const float*)d_in[4];
  const float* w3   = (const float*)d_in[5];
  const float* b3   = (const float*)d_in[6];
  const float* w4   = (const float*)d_in[7];
  const float* b4   = (const float*)d_in[8];
  const float* wih0 = (const float*)d_in[9];
  const float* whh0 = (const float*)d_in[10];
  const float* bih0 = (const float*)d_in[11];
  const float* bhh0 = (const float*)d_in[12];
  const float* wih1 = (const float*)d_in[13];
  const float* whh1 = (const float*)d_in[14];
  const float* bih1 = (const float*)d_in[15];
  const float* bhh1 = (const float*)d_in[16];
  const float* wfc  = (const float*)d_in[17];
  const float* bfc  = (const float*)d_in[18];

  char* p = (char*)d_ws;
  half_t* w1b  = (half_t*)p; p += (size_t)2048 * 4864 * 2;
  half_t* w2b  = (half_t*)p; p += (size_t)1024 * 2048 * 2;
  half_t* w3b  = (half_t*)p; p += (size_t)512 * 1024 * 2;
  half_t* w4b  = (half_t*)p; p += (size_t)256 * 512 * 2;
  half_t* wi0b = (half_t*)p; p += (size_t)48 * 4096 * 2;   // gate-contiguous B-frag order
  half_t* wh0b = (half_t*)p; p += (size_t)48 * 4096 * 2;
  half_t* wi1b = (half_t*)p; p += (size_t)48 * 4096 * 2;
  half_t* wh1b = (half_t*)p; p += (size_t)48 * 4096 * 2;
  half_t* wfcb = (half_t*)p; p += (size_t)3 * 4096 * 2;
  float* e1 = (float*)p; p += (size_t)8192 * 2048 * 4;
  float* e2 = (float*)p; p += (size_t)8192 * 1024 * 4;
  float* e3 = (float*)p; p += (size_t)8192 * 512 * 4;
  float* e4 = (float*)p; p += (size_t)8192 * 256 * 4;

  conv(w1, w1b, 2048, 4860, 2048, 4864, stream);
  conv(w2, w2b, 1024, 2048, 1024, 2048, stream);
  conv(w3, w3b, 512, 1024, 512, 1024, stream);
  conv(w4, w4b, 256, 512, 256, 512, stream);
  repk3(wih0, wi0b, stream);
  repk3(whh0, wh0b, stream);
  repk3(wih1, wi1b, stream);
  repk3(whh1, wh1b, stream);
  repk(wfc, wfcb, 3, 42, stream);

  gemm_bias_relu<<<dim3(64, 16), 256, 0, stream>>>(x, 4860, 4860, w1b, 4864, b1, e1, 2048, 4864);
  gemm_bias_relu<<<dim3(64, 8),  256, 0, stream>>>(e1, 2048, 2048, w2b, 2048, b2, e2, 1024, 2048);
  gemm_bias_relu<<<dim3(64, 4),  256, 0, stream>>>(e2, 1024, 1024, w3b, 1024, b3, e3, 512, 1024);
  gemm_bias_relu<<<dim3(64, 2),  256, 0, stream>>>(e3, 512, 512, w4b, 512, b4, e4, 256, 512);

  gru_fused<<<256, 1024, 0, stream>>>(e4, wi0b, wh0b, wi1b, wh1b,
                                      bih0, bhh0, bih1, bhh1, wfcb, bfc, (float*)d_out);
}

// Round 4
// 4289.640 us; speedup vs baseline: 1.9562x; 1.4150x over previous
//
#include <hip/hip_runtime.h>
#include <stdint.h>
#include <stddef.h>

typedef _Float16 half_t;
typedef __attribute__((ext_vector_type(8))) _Float16 halfx8;
typedef __attribute__((ext_vector_type(4))) float floatx4;

__device__ __forceinline__ float sigmoidf_(float x) { return 1.f / (1.f + __expf(-x)); }
__device__ __forceinline__ float tanhf_(float x) {
  x = fminf(fmaxf(x, -15.f), 15.f);
  float e = __expf(2.f * x);
  return (e - 1.f) / (e + 1.f);
}

__device__ __forceinline__ floatx4 mfma16(halfx8 a, halfx8 b, floatx4 c) {
  return __builtin_amdgcn_mfma_f32_16x16x32_f16(a, b, c, 0, 0, 0);
}

// Counted-vmcnt wait (T4). sched_barrier(0) after the wait is REQUIRED (rule 18).
__device__ __forceinline__ void waitv6() {
  asm volatile("s_waitcnt vmcnt(6)" ::: "memory");
  __builtin_amdgcn_sched_barrier(0);
}
__device__ __forceinline__ void waitv0() {
  asm volatile("s_waitcnt vmcnt(0)" ::: "memory");
  __builtin_amdgcn_sched_barrier(0);
}

// LDS-only barrier: weight loads live in registers, so vmcnt need NOT drain.
// (__syncthreads would emit s_waitcnt vmcnt(0) and collapse the pipeline.)
__device__ __forceinline__ void bar_lds() {
  asm volatile("s_waitcnt lgkmcnt(0)" ::: "memory");
  __builtin_amdgcn_s_barrier();
  asm volatile("" ::: "memory");
}

// Three 16B weight-fragment loads off one base (gates at +0/+16/+32 bytes).
// Inline asm: compiler does not track these; the counted waits above do.
#define GLOAD3(d0, d1, d2, p)                                          \
  asm volatile("global_load_dwordx4 %0, %3, off\n\t"                   \
               "global_load_dwordx4 %1, %3, off offset:16\n\t"         \
               "global_load_dwordx4 %2, %3, off offset:32"             \
               : "=&v"(d0), "=&v"(d1), "=&v"(d2)                       \
               : "v"(p)                                                \
               : "memory")

// ---------------- fp32 -> fp16 convert with optional row/col zero-pad ----------------
__global__ void convert_pad(const float* __restrict__ src, half_t* __restrict__ dst,
                            int srcRows, int srcCols, int dstRows, int dstCols) {
  int total = dstRows * dstCols;
  for (int i = blockIdx.x * blockDim.x + threadIdx.x; i < total; i += gridDim.x * blockDim.x) {
    int r = i / dstCols, c = i - r * dstCols;
    float v = (r < srcRows && c < srcCols) ? src[(size_t)r * srcCols + c] : 0.f;
    dst[i] = (half_t)v;
  }
}

// ---------------- repack W (rows x 256, fp32) into MFMA B-frag order -------------------
// dst[nt][ks][lane][j] = W[nt*16 + (lane&15)][ks*32 + (lane>>4)*8 + j], fp16.
// (used for the small FC weight)
__global__ void repack_bfrag(const float* __restrict__ src, half_t* __restrict__ dst,
                             int ntCount, int srcRows) {
  int total = ntCount * 8 * 64 * 8;
  for (int i = blockIdx.x * blockDim.x + threadIdx.x; i < total; i += gridDim.x * blockDim.x) {
    int j = i & 7, lane = (i >> 3) & 63, ks = (i >> 9) & 7, nt = i >> 12;
    int q = lane >> 4, m15 = lane & 15;
    int row = nt * 16 + m15;
    int col = ks * 32 + q * 8 + j;
    float v = (row < srcRows) ? src[(size_t)row * 256 + col] : 0.f;
    dst[i] = (half_t)v;
  }
}

// ---------------- repack GRU W (768 x 256, fp32) gate-contiguous B-frag order ----------
// dst[((w*8+ks)*64 + lane)*24 + g*8 + j] = W[g*256 + w*16 + (lane&15)][ks*32 + (lane>>4)*8 + j]
__global__ void repack_bfrag3(const float* __restrict__ src, half_t* __restrict__ dst,
                              int wCount) {
  int total = wCount * 8 * 64 * 24;
  for (int i = blockIdx.x * blockDim.x + threadIdx.x; i < total; i += gridDim.x * blockDim.x) {
    int j = i & 7;
    int g = (i >> 3) % 3;
    int rest = i / 24;          // lane + 64*ks + 512*w
    int lane = rest & 63;
    int ks = (rest >> 6) & 7;
    int w = rest >> 9;
    int q = lane >> 4, m15 = lane & 15;
    int row = g * 256 + w * 16 + m15;
    int col = ks * 32 + q * 8 + j;
    dst[i] = (half_t)src[(size_t)row * 256 + col];
  }
}

// ---------------- GEMM: C(MxN,fp32) = relu(A(MxKa,fp32) * B(NxKp,fp16)^T + bias) ------
__global__ __launch_bounds__(256) void gemm_bias_relu(
    const float* __restrict__ A, int lda, int Ka,
    const half_t* __restrict__ B, int ldb,
    const float* __restrict__ bias,
    float* __restrict__ C, int N, int Kp) {
  __shared__ half_t As[128 * 64];
  __shared__ half_t Bs[128 * 64];
  const int t = threadIdx.x;
  const int w = t >> 6, l = t & 63;
  const int q = l >> 4, m15 = l & 15;
  const int rowBase = blockIdx.x * 128, colBase = blockIdx.y * 128;
  const int wm = (w >> 1) * 64, wn = (w & 1) * 64;
  const floatx4 z4 = {0.f, 0.f, 0.f, 0.f};
  floatx4 acc[4][4];
#pragma unroll
  for (int i = 0; i < 4; ++i)
#pragma unroll
    for (int j = 0; j < 4; ++j) acc[i][j] = z4;

  const int sr = t >> 3;
  const int sc = (t & 7) * 8;

  for (int k0 = 0; k0 < Kp; k0 += 64) {
    __syncthreads();
    const bool full = (k0 + 64 <= Ka);
#pragma unroll
    for (int p = 0; p < 4; ++p) {
      const int r = p * 32 + sr;
      halfx8 tmp;
      if (full) {
        const float4* s0 = (const float4*)(A + (size_t)(rowBase + r) * lda + k0 + sc);
        float4 f0 = s0[0], f1 = s0[1];
        tmp[0] = (half_t)f0.x; tmp[1] = (half_t)f0.y; tmp[2] = (half_t)f0.z; tmp[3] = (half_t)f0.w;
        tmp[4] = (half_t)f1.x; tmp[5] = (half_t)f1.y; tmp[6] = (half_t)f1.z; tmp[7] = (half_t)f1.w;
      } else {
#pragma unroll
        for (int j2 = 0; j2 < 8; ++j2) {
          int kk = k0 + sc + j2;
          tmp[j2] = (half_t)(kk < Ka ? A[(size_t)(rowBase + r) * lda + kk] : 0.f);
        }
      }
      *(halfx8*)(&As[r * 64 + sc]) = tmp;
    }
#pragma unroll
    for (int p = 0; p < 4; ++p) {
      const int chunk = p * 256 + t;
      const int r = chunk >> 3, cc = (chunk & 7) * 8;
      *(halfx8*)(&Bs[r * 64 + cc]) =
          *(const halfx8*)(B + (size_t)(colBase + r) * ldb + k0 + cc);
    }
    __syncthreads();
#pragma unroll
    for (int kk = 0; kk < 2; ++kk) {
      const int ko = kk * 32 + q * 8;
      halfx8 af[4], bfr[4];
#pragma unroll
      for (int i = 0; i < 4; ++i) af[i] = *(const halfx8*)(&As[(wm + i * 16 + m15) * 64 + ko]);
#pragma unroll
      for (int j = 0; j < 4; ++j) bfr[j] = *(const halfx8*)(&Bs[(wn + j * 16 + m15) * 64 + ko]);
#pragma unroll
      for (int i = 0; i < 4; ++i)
#pragma unroll
        for (int j = 0; j < 4; ++j) acc[i][j] = mfma16(af[i], bfr[j], acc[i][j]);
    }
  }
#pragma unroll
  for (int j = 0; j < 4; ++j) {
    const int n = colBase + wn + j * 16 + m15;
    const float bv = bias[n];
#pragma unroll
    for (int i = 0; i < 4; ++i)
#pragma unroll
      for (int r = 0; r < 4; ++r) {
        const int m = rowBase + wm + i * 16 + q * 4 + r;
        C[(size_t)m * N + n] = fmaxf(acc[i][j][r] + bv, 0.f);
      }
  }
}

// ---------------- fused persistent GRU (2 layers) + FC + softmax ----------------
// 256 blocks x 1024 thr (16 waves), 1 block/CU, 32 batch rows/block, 128 steps.
// THE pipeline invariant: vmcnt never drains below 6 for the whole kernel.
//  - uniform half-iters: ks<6 reload this layer's bank ks+2; ks=6/7 issue the
//    NEXT layer's banks A/B (weight addresses are static).
//  - barriers are raw s_barrier + lgkmcnt(0) only (weight loads land in regs).
//  - no compiler-tracked global VMEM inside the loop (wfc in LDS, biases in regs)
//    so the compiler never inserts its own vmcnt(0).
//  - FC(t-1) runs on waves 0-5 during the L0 phase; softmax(t-1) on waves 6-9
//    during the L1 phase -> 2 barriers/step, FC/softmax off the critical path.
#define HLD 264  // 264*2B = 528B row stride: 16B-aligned halfx8 rows, 2-way-free banks

#define HI(KS, W0, W1, W2, V0, V1, V2, PI, PH)                                   \
  {                                                                              \
    const int ko = (KS) * 32 + q * 8;                                            \
    halfx8 x0 = *(const halfx8*)(&X[m15 * HLD + ko]);                            \
    halfx8 x1 = *(const halfx8*)(&X[(16 + m15) * HLD + ko]);                     \
    halfx8 h0 = *(const halfx8*)(&Hold[m15 * HLD + ko]);                         \
    halfx8 h1 = *(const halfx8*)(&Hold[(16 + m15) * HLD + ko]);                  \
    waitv6();                                                                    \
    accR[0] = mfma16(x0, W0, accR[0]);   accR[1] = mfma16(x1, W0, accR[1]);      \
    accZ[0] = mfma16(x0, W1, accZ[0]);   accZ[1] = mfma16(x1, W1, accZ[1]);      \
    accNi[0] = mfma16(x0, W2, accNi[0]); accNi[1] = mfma16(x1, W2, accNi[1]);    \
    accR[0] = mfma16(h0, V0, accR[0]);   accR[1] = mfma16(h1, V0, accR[1]);      \
    accZ[0] = mfma16(h0, V1, accZ[0]);   accZ[1] = mfma16(h1, V1, accZ[1]);      \
    accNh[0] = mfma16(h0, V2, accNh[0]); accNh[1] = mfma16(h1, V2, accNh[1]);    \
    GLOAD3(W0, W1, W2, (PI));                                                    \
    GLOAD3(V0, V1, V2, (PH));                                                    \
  }

#define LAYER(Xp, Holdp, Hnewp, BI, BH, NBI, NBH, HREG, BR, BZ, BIN, BHN)        \
  {                                                                              \
    const half_t* X = (Xp);                                                      \
    const half_t* Hold = (Holdp);                                                \
    half_t* Hnew = (Hnewp);                                                      \
    const half_t* bi_ = (BI);                                                    \
    const half_t* bh_ = (BH);                                                    \
    floatx4 accR[2] = {z4, z4}, accZ[2] = {z4, z4};                              \
    floatx4 accNi[2] = {z4, z4}, accNh[2] = {z4, z4};                            \
    HI(0, aw0, aw1, aw2, av0, av1, av2, bi_ + 2 * 1536, bh_ + 2 * 1536)          \
    HI(1, bw0, bw1, bw2, bv0, bv1, bv2, bi_ + 3 * 1536, bh_ + 3 * 1536)          \
    HI(2, aw0, aw1, aw2, av0, av1, av2, bi_ + 4 * 1536, bh_ + 4 * 1536)          \
    HI(3, bw0, bw1, bw2, bv0, bv1, bv2, bi_ + 5 * 1536, bh_ + 5 * 1536)          \
    HI(4, aw0, aw1, aw2, av0, av1, av2, bi_ + 6 * 1536, bh_ + 6 * 1536)          \
    HI(5, bw0, bw1, bw2, bv0, bv1, bv2, bi_ + 7 * 1536, bh_ + 7 * 1536)          \
    HI(6, aw0, aw1, aw2, av0, av1, av2, (NBI), (NBH))                            \
    HI(7, bw0, bw1, bw2, bv0, bv1, bv2, (NBI) + 1536, (NBH) + 1536)              \
    const int col = w * 16 + m15;                                                \
    _Pragma("unroll")                                                            \
    for (int mt = 0; mt < 2; ++mt)                                               \
      _Pragma("unroll")                                                          \
      for (int r = 0; r < 4; ++r) {                                              \
        const float rr = sigmoidf_(accR[mt][r] + (BR));                          \
        const float zz = sigmoidf_(accZ[mt][r] + (BZ));                          \
        const float nn = tanhf_(accNi[mt][r] + (BIN) + rr * (accNh[mt][r] + (BHN))); \
        float hv = HREG[mt][r];                                                  \
        hv = (1.f - zz) * nn + zz * hv;                                          \
        HREG[mt][r] = hv;                                                        \
        Hnew[(mt * 16 + q * 4 + r) * HLD + col] = (half_t)hv;                    \
      }                                                                          \
  }

#define FC_BODY                                                                  \
  {                                                                              \
    floatx4 a = z4;                                                              \
    _Pragma("unroll")                                                            \
    for (int ks = 0; ks < 8; ++ks) {                                             \
      const int ko = ks * 32 + q * 8;                                            \
      const halfx8 wf = *(const halfx8*)(&wfcs[((size_t)(fcct * 8 + ks) * 64 + lane) * 8]); \
      const halfx8 hf = *(const halfx8*)(&pX1[(fcmt * 16 + m15) * HLD + ko]);    \
      a = mfma16(hf, wf, a);                                                     \
    }                                                                            \
    _Pragma("unroll")                                                            \
    for (int r = 0; r < 4; ++r)                                                  \
      lg[(fcmt * 16 + q * 4 + r) * 48 + fccol] =                                 \
          (fccol < 42) ? fmaxf(a[r] + bfcv, 0.f) : -1e30f;                       \
  }

#define SM_BODY(TSIDX)                                                           \
  {                                                                              \
    const int local = t - 384, row = local >> 3, s = local & 7;                  \
    float v[6];                                                                  \
    _Pragma("unroll")                                                            \
    for (int k2 = 0; k2 < 6; ++k2) v[k2] = lg[row * 48 + s + k2 * 8];            \
    float mx = v[0];                                                             \
    _Pragma("unroll")                                                            \
    for (int k2 = 1; k2 < 6; ++k2) mx = fmaxf(mx, v[k2]);                        \
    _Pragma("unroll")                                                            \
    for (int d = 1; d < 8; d <<= 1) mx = fmaxf(mx, __shfl_xor(mx, d, 8));        \
    float sm = 0.f;                                                              \
    _Pragma("unroll")                                                            \
    for (int k2 = 0; k2 < 6; ++k2) { v[k2] = __expf(v[k2] - mx); sm += v[k2]; }  \
    _Pragma("unroll")                                                            \
    for (int d = 1; d < 8; d <<= 1) sm += __shfl_xor(sm, d, 8);                  \
    const float inv = 1.f / sm;                                                  \
    const size_t base = ((size_t)(rowBase + row) * 128 + (TSIDX)) * 42;          \
    _Pragma("unroll")                                                            \
    for (int k2 = 0; k2 < 6; ++k2) {                                             \
      const int col = s + k2 * 8;                                                \
      if (col < 42) out[base + col] = v[k2] * inv;                               \
    }                                                                            \
  }

__global__ __launch_bounds__(1024) void gru_fused(
    const float* __restrict__ e,
    const half_t* __restrict__ wih0, const half_t* __restrict__ whh0,
    const half_t* __restrict__ wih1, const half_t* __restrict__ whh1,
    const float* __restrict__ bih0, const float* __restrict__ bhh0,
    const float* __restrict__ bih1, const float* __restrict__ bhh1,
    const half_t* __restrict__ wfc, const float* __restrict__ bfc,
    float* __restrict__ out) {
  __shared__ half_t hbuf[3][32 * HLD];
  __shared__ half_t zh[32 * HLD];          // zeroed h(-1): keeps the schedule uniform
  __shared__ half_t wfcs[3 * 8 * 64 * 8];  // FC weights in LDS -> no VMEM in FC
  __shared__ float lg[32 * 48];
  const int t = threadIdx.x;
  const int w = t >> 6, lane = t & 63;
  const int q = lane >> 4, m15 = lane & 15;
  const int rowBase = blockIdx.x * 32;
  const floatx4 z4 = {0.f, 0.f, 0.f, 0.f};

  // per-thread gate biases (no global loads inside the step loop!)
  const int bcol = w * 16 + m15;
  const float br0 = bih0[bcol] + bhh0[bcol];
  const float bz0 = bih0[256 + bcol] + bhh0[256 + bcol];
  const float bi0v = bih0[512 + bcol];
  const float bh0v = bhh0[512 + bcol];
  const float br1 = bih1[bcol] + bhh1[bcol];
  const float bz1 = bih1[256 + bcol] + bhh1[256 + bcol];
  const float bi1v = bih1[512 + bcol];
  const float bh1v = bhh1[512 + bcol];
  // FC assignment: waves 0-5, (col-tile, row-tile) = (w>>1, w&1)
  const int fcct = w >> 1, fcmt = w & 1;
  const int fccol = fcct * 16 + m15;
  float bfcv = 0.f;
  if (w < 6 && fccol < 42) bfcv = bfc[fccol];

  // stage wfc into LDS (6144 dwords), zero zh (4224 dwords), stage x0 = e
  for (int i = t; i < 6144; i += 1024)
    ((uint32_t*)wfcs)[i] = ((const uint32_t*)wfc)[i];
  for (int i = t; i < (32 * HLD) / 2; i += 1024) ((uint32_t*)zh)[i] = 0u;
  for (int i = t; i < 32 * 256; i += 1024) {
    const int r = i >> 8, c = i & 255;
    hbuf[0][r * HLD + c] = (half_t)e[(size_t)(rowBase + r) * 256 + c];
  }
  __syncthreads();  // pre-loop only; nothing of ours is in flight yet

  float h0old[2][4] = {};
  float h1old[2][4] = {};

  // per-lane weight bases (gate-contiguous repack: lane chunk = 24 halves)
  const half_t* bi0p = wih0 + ((size_t)(w * 8) * 64 + lane) * 24;
  const half_t* bh0p = whh0 + ((size_t)(w * 8) * 64 + lane) * 24;
  const half_t* bi1p = wih1 + ((size_t)(w * 8) * 64 + lane) * 24;
  const half_t* bh1p = whh1 + ((size_t)(w * 8) * 64 + lane) * 24;

  // persistent 2-bank weight ring
  halfx8 aw0, aw1, aw2, av0, av1, av2;
  halfx8 bw0, bw1, bw2, bv0, bv1, bv2;
  GLOAD3(aw0, aw1, aw2, bi0p);
  GLOAD3(av0, av1, av2, bh0p);
  GLOAD3(bw0, bw1, bw2, bi0p + 1536);
  GLOAD3(bv0, bv1, bv2, bh0p + 1536);

  // rotating buffers: pX1 = h1_old (= x_t), pX0 = h0_old, pF = free
  half_t* pX1 = hbuf[0];
  half_t* pX0 = hbuf[1];
  half_t* pF = hbuf[2];

#pragma unroll 1
  for (int ts = 0; ts < 128; ++ts) {
    // ---- layer 0 (+ FC(ts-1) on waves 0-5) ----
    LAYER(pX1, ts ? pX0 : zh, pF, bi0p, bh0p, bi1p, bh1p, h0old, br0, bz0, bi0v, bh0v)
    if (ts && w < 6) FC_BODY
    bar_lds();
    // ---- layer 1 (+ softmax(ts-1) on waves 6-9) ----
    LAYER(pF, ts ? pX1 : zh, pX0, bi1p, bh1p, bi0p, bh0p, h1old, br1, bz1, bi1v, bh1v)
    if (ts && w >= 6 && w < 10) SM_BODY(ts - 1)
    bar_lds();
    // rotate: h1_old <- pX0 (h1_new), h0_old <- pF (h0_new), free <- pX1
    half_t* tmp = pX1; pX1 = pX0; pX0 = pF; pF = tmp;
  }

  // final FC + softmax for ts=127 (pX1 = h1(127) after last rotate)
  if (w < 6) FC_BODY
  bar_lds();
  if (w >= 6 && w < 10) SM_BODY(127)
  waitv0();  // drain the dummy prefetch + stores before endpgm
}

// ---------------- host launch ----------------
static inline void conv(const float* s, half_t* d, int sr, int sc, int dr, int dc,
                        hipStream_t st) {
  int total = dr * dc;
  int blocks = (total + 255) / 256;
  if (blocks > 4096) blocks = 4096;
  convert_pad<<<blocks, 256, 0, st>>>(s, d, sr, sc, dr, dc);
}

static inline void repk(const float* s, half_t* d, int ntCount, int srcRows, hipStream_t st) {
  int total = ntCount * 8 * 64 * 8;
  int blocks = (total + 255) / 256;
  repack_bfrag<<<blocks, 256, 0, st>>>(s, d, ntCount, srcRows);
}

static inline void repk3(const float* s, half_t* d, hipStream_t st) {
  int total = 16 * 8 * 64 * 24;
  int blocks = (total + 255) / 256;
  repack_bfrag3<<<blocks, 256, 0, st>>>(s, d, 16);
}

extern "C" void kernel_launch(void* const* d_in, const int* in_sizes, int n_in,
                              void* d_out, int out_size, void* d_ws, size_t ws_size,
                              hipStream_t stream) {
  const float* x    = (const float*)d_in[0];
  const float* w1   = (const float*)d_in[1];
  const float* b1   = (const float*)d_in[2];
  const float* w2   = (const float*)d_in[3];
  const float* b2   = (const float*)d_in[4];
  const float* w3   = (const float*)d_in[5];
  const float* b3   = (const float*)d_in[6];
  const float* w4   = (const float*)d_in[7];
  const float* b4   = (const float*)d_in[8];
  const float* wih0 = (const float*)d_in[9];
  const float* whh0 = (const float*)d_in[10];
  const float* bih0 = (const float*)d_in[11];
  const float* bhh0 = (const float*)d_in[12];
  const float* wih1 = (const float*)d_in[13];
  const float* whh1 = (const float*)d_in[14];
  const float* bih1 = (const float*)d_in[15];
  const float* bhh1 = (const float*)d_in[16];
  const float* wfc  = (const float*)d_in[17];
  const float* bfc  = (const float*)d_in[18];

  char* p = (char*)d_ws;
  half_t* w1b  = (half_t*)p; p += (size_t)2048 * 4864 * 2;
  half_t* w2b  = (half_t*)p; p += (size_t)1024 * 2048 * 2;
  half_t* w3b  = (half_t*)p; p += (size_t)512 * 1024 * 2;
  half_t* w4b  = (half_t*)p; p += (size_t)256 * 512 * 2;
  half_t* wi0b = (half_t*)p; p += (size_t)48 * 4096 * 2;   // gate-contiguous B-frag order
  half_t* wh0b = (half_t*)p; p += (size_t)48 * 4096 * 2;
  half_t* wi1b = (half_t*)p; p += (size_t)48 * 4096 * 2;
  half_t* wh1b = (half_t*)p; p += (size_t)48 * 4096 * 2;
  half_t* wfcb = (half_t*)p; p += (size_t)3 * 4096 * 2;
  float* e1 = (float*)p; p += (size_t)8192 * 2048 * 4;
  float* e2 = (float*)p; p += (size_t)8192 * 1024 * 4;
  float* e3 = (float*)p; p += (size_t)8192 * 512 * 4;
  float* e4 = (float*)p; p += (size_t)8192 * 256 * 4;

  conv(w1, w1b, 2048, 4860, 2048, 4864, stream);
  conv(w2, w2b, 1024, 2048, 1024, 2048, stream);
  conv(w3, w3b, 512, 1024, 512, 1024, stream);
  conv(w4, w4b, 256, 512, 256, 512, stream);
  repk3(wih0, wi0b, stream);
  repk3(whh0, wh0b, stream);
  repk3(wih1, wi1b, stream);
  repk3(whh1, wh1b, stream);
  repk(wfc, wfcb, 3, 42, stream);

  gemm_bias_relu<<<dim3(64, 16), 256, 0, stream>>>(x, 4860, 4860, w1b, 4864, b1, e1, 2048, 4864);
  gemm_bias_relu<<<dim3(64, 8),  256, 0, stream>>>(e1, 2048, 2048, w2b, 2048, b2, e2, 1024, 2048);
  gemm_bias_relu<<<dim3(64, 4),  256, 0, stream>>>(e2, 1024, 1024, w3b, 1024, b3, e3, 512, 1024);
  gemm_bias_relu<<<dim3(64, 2),  256, 0, stream>>>(e3, 512, 512, w4b, 512, b4, e4, 256, 512);

  gru_fused<<<256, 1024, 0, stream>>>(e4, wi0b, wh0b, wi1b, wh1b,
                                      bih0, bhh0, bih1, bhh1, wfcb, bfc, (float*)d_out);
}